// Round 5
// baseline (164.694 us; speedup 1.0000x reference)
//
#include <hip/hip_runtime.h>
#include <math.h>

#define T_LEN      24000
#define TS         1792          // samples per slice
#define NSLICE     14            // 14 * 1792 = 25088 >= 24000 (last slice: 704 valid)
#define W_LEN      81
#define HALF_W     40
#define NK         21
#define MAXORD     10
#define NIMG_TOTAL 1561          // |{k in [-10,10]^3 : |kx|+|ky|+|kz| <= 10}|
#define FS_F       48000.0f
#define C_F        343.0f
#define FS_OVER_C  (48000.0f / 343.0f)
#define PI_F       3.14159265358979323846f
#define FOUR_PI_F  12.566370614359172f
#define NEG_SLOPE  0.01f
#define NTHREADS   512
#define NWAVES     8
#define ACC_STRIDE 1796          // TS + 4: copies start on different banks
#define DYN_LDS    (NWAVES * ACC_STRIDE * 4)   // 57472 B (8 private slice copies)

// ---- compile-time table of valid image triples ----
// entry: (order << 15) | (kxi << 10) | (kyi << 5) | kzi
struct Table { unsigned int e[NIMG_TOTAL]; };

constexpr Table make_table() {
    Table t{};
    int n = 0;
    for (int kx = 0; kx < NK; ++kx)
        for (int ky = 0; ky < NK; ++ky)
            for (int kz = 0; kz < NK; ++kz) {
                int ax = kx >= MAXORD ? kx - MAXORD : MAXORD - kx;
                int ay = ky >= MAXORD ? ky - MAXORD : MAXORD - ky;
                int az = kz >= MAXORD ? kz - MAXORD : MAXORD - kz;
                int order = ax + ay + az;
                if (order <= MAXORD)
                    t.e[n++] = (unsigned)((order << 15) | (kx << 10) | (ky << 5) | kz);
            }
    return t;
}
__constant__ Table g_tbl = make_table();

__global__ __launch_bounds__(NTHREADS)
void rir_balanced_kernel(const float* __restrict__ g_in,
                         const float* __restrict__ W1, const float* __restrict__ b1,
                         const float* __restrict__ W2, const float* __restrict__ b2,
                         const float* __restrict__ W3, const float* __restrict__ b3,
                         float* __restrict__ out_rir, float* __restrict__ out_origin)
{
    extern __shared__ float acc[];                   // NWAVES * ACC_STRIDE (57472 B)
    __shared__ float2 params[NIMG_TOTAL + 7];        // (amp, delay)
    __shared__ float hann[W_LEN];
    __shared__ float dsq[3 * NK];                    // (img - mic)^2 per axis
    __shared__ float bp[MAXORD + 1];                 // 0.9^o / (4*pi)
    __shared__ float h1[30], h2[20], zb[9], sm_in[22], rms[9];
    __shared__ int cnt;

    const int tid  = threadIdx.x;
    const int lane = tid & 63;
    const int wave = tid >> 6;
    const int s    = blockIdx.x;         // time slice
    const int b    = blockIdx.y;         // batch row
    const int lo   = s * TS;
    const int nout = min(TS, T_LEN - lo);

    // ---- zero the 8 private accumulators ----
    for (int i = tid; i < NWAVES * ACC_STRIDE; i += NTHREADS) acc[i] = 0.0f;

    // ---- small tables (waves 2-5), counter ----
    if (tid >= 128 && tid < 128 + W_LEN) {
        int j = tid - 128;
        hann[j] = 0.5f * (1.0f - cosf(2.0f * PI_F * (float)j / 80.0f));
    }
    if (tid >= 256 && tid <= 256 + MAXORD)
        bp[tid - 256] = powf(0.9f, (float)(tid - 256)) * (1.0f / FOUR_PI_F);
    if (tid == 320) cnt = 0;

    // ---- wave 0: input row, MLP, geometry (in-wave LDS ordering) ----
    if (tid < 64) {
        if (tid < 22) sm_in[tid] = g_in[b * 22 + tid];
        if (tid < 30) {
            float a = b1[tid];
            const float* w = W1 + tid * 22;
            #pragma unroll
            for (int i = 0; i < 22; ++i) a += sm_in[i] * w[i];
            h1[tid] = (a >= 0.0f) ? a : NEG_SLOPE * a;
        }
        if (tid < 20) {
            float a = b2[tid];
            const float* w = W2 + tid * 30;
            #pragma unroll
            for (int i = 0; i < 30; ++i) a += h1[i] * w[i];
            h2[tid] = (a >= 0.0f) ? a : NEG_SLOPE * a;
        }
        if (tid < 9) {
            float a = b3[tid];
            const float* w = W3 + tid * 20;
            #pragma unroll
            for (int i = 0; i < 20; ++i) a += h2[i] * w[i];
            zb[tid] = 1.0f / (1.0f + expf(-a));
        }
        if (tid < 3) {
            float room = zb[tid] * 20.0f;
            rms[tid]     = room;
            rms[3 + tid] = zb[3 + tid] * room;   // mic
            rms[6 + tid] = zb[6 + tid] * room;   // src
        }
        if (tid == 0 && s == 0) {
            float dx = rms[3] - rms[6], dy = rms[4] - rms[7], dz = rms[5] - rms[8];
            out_origin[b] = 40.0f + FS_F * sqrtf(dx * dx + dy * dy + dz * dz) / C_F;
        }
        if (tid < 3 * NK) {
            int a  = tid / NK;
            int kk = (tid - a * NK) - MAXORD;
            float L = rms[a], src = rms[6 + a];
            float img = ((kk & 1) == 0) ? (float)kk * L + src : (float)(kk + 1) * L - src;
            float diff = img - rms[3 + a];
            dsq[tid] = diff * diff;
        }
    }
    __syncthreads();

    // ---- enumerate valid images whose window touches this slice ----
    // touch iff t0 >= lo-40 && t0 <= lo+nout+39  (t0 integer-valued)
    const float lof = (float)lo - 40.5f;
    const float hif = (float)(lo + nout) + 39.5f;
    for (int i = tid; i < NIMG_TOTAL; i += NTHREADS) {
        unsigned e = g_tbl.e[i];
        int kzi = e & 31, kyi = (e >> 5) & 31, kxi = (e >> 10) & 31, order = (int)(e >> 15);
        float d     = sqrtf(dsq[kxi] + dsq[NK + kyi] + dsq[2 * NK + kzi]);
        float delay = 40.0f + d * FS_OVER_C;
        float t0f   = floorf(delay);
        if (t0f > lof && t0f < hif) {
            float amp = bp[order] * __builtin_amdgcn_rcpf(fmaxf(d, 0.001f));
            int pos = atomicAdd(&cnt, 1);
            params[pos] = make_float2(amp, delay);
        }
    }
    __syncthreads();

    // ---- lane-parallel taps, wave-round-robin images, wave-private LDS copy ----
    // Lane handles taps j0 = (lane - ws) mod 64 and j0+64 (if <= 80); consecutive
    // lanes hit consecutive LDS addresses -> conflict-free ds_add. Worst wave
    // processes <= cnt/8 images even under full image pileup.
    const int n = cnt;
    float* accw = acc + wave * ACC_STRIDE;
    for (int i = wave; i < n; i += NWAVES) {
        float2 p   = params[i];                  // uniform-address broadcast read
        float t0f  = floorf(p.y);
        float frac = p.y - t0f;
        float sp   = __sinf(PI_F * frac);
        int   ws   = (int)t0f - HALF_W;          // window start (global sample)
        int   j0   = (lane - ws) & 63;           // two's complement -> correct mod 64
        int   sl   = ws + j0 - lo;               // local sample of tap j0
        int   n1   = j0 - HALF_W;
        float x1   = (float)n1 - frac;           // t - delay
        float sg   = (n1 & 1) ? sp : -sp;        // sin(pi(n-frac)) = -(-1)^n sin(pi frac)
        float sv1  = (x1 == 0.0f) ? 1.0f : sg * __builtin_amdgcn_rcpf(PI_F * x1);
        if ((unsigned)sl < (unsigned)nout)
            atomicAdd(&accw[sl], p.x * sv1 * hann[j0]);
        if (j0 <= W_LEN - 65) {                  // second tap j = j0+64 (parity unchanged)
            int   sl2 = sl + 64;
            float x2  = x1 + 64.0f;              // >= 23, never 0
            float sv2 = sg * __builtin_amdgcn_rcpf(PI_F * x2);
            if ((unsigned)sl2 < (unsigned)nout)
                atomicAdd(&accw[sl2], p.x * sv2 * hann[j0 + 64]);
        }
    }
    __syncthreads();

    // ---- tree-combine the 8 copies, write coalesced ----
    float* outp = out_rir + (size_t)b * T_LEN + lo;
    for (int m = tid; m < nout; m += NTHREADS) {
        float v = 0.0f;
        #pragma unroll
        for (int w = 0; w < NWAVES; ++w) v += acc[w * ACC_STRIDE + m];
        outp[m] = v;
    }
}

extern "C" void kernel_launch(void* const* d_in, const int* in_sizes, int n_in,
                              void* d_out, int out_size, void* d_ws, size_t ws_size,
                              hipStream_t stream) {
    const float* g_in = (const float*)d_in[0];
    const float* W1   = (const float*)d_in[1];
    const float* b1   = (const float*)d_in[2];
    const float* W2   = (const float*)d_in[3];
    const float* b2   = (const float*)d_in[4];
    const float* W3   = (const float*)d_in[5];
    const float* b3   = (const float*)d_in[6];

    const int B = in_sizes[0] / 22;

    float* out_rir    = (float*)d_out;
    float* out_origin = out_rir + (size_t)B * T_LEN;

    // static (~14 KB) + dynamic (57 KB) ~ 71 KB LDS -> 2 blocks/CU on gfx950
    (void)hipFuncSetAttribute((const void*)rir_balanced_kernel,
                              hipFuncAttributeMaxDynamicSharedMemorySize,
                              DYN_LDS);

    dim3 grid(NSLICE, B);
    rir_balanced_kernel<<<grid, NTHREADS, DYN_LDS, stream>>>(
        g_in, W1, b1, W2, b2, W3, b3, out_rir, out_origin);
}